// Round 4
// baseline (186.891 us; speedup 1.0000x reference)
//
#include <hip/hip_runtime.h>
#include <math.h>

namespace {
constexpr int S  = 2048;
constexpr int E  = 1024;
constexpr int NH = 8;
constexpr int DH = 128;
constexpr float EPSF = 1e-6f;
constexpr float INV_LN2 = 1.4426950408889634f;
}

typedef short short8 __attribute__((ext_vector_type(8)));
typedef float f32x16 __attribute__((ext_vector_type(16)));
typedef float f32x4  __attribute__((ext_vector_type(4)));

__device__ __forceinline__ unsigned short f2bf(float x) {
  unsigned int u = __float_as_uint(x);
  unsigned int r = (u + 0x7fffu + ((u >> 16) & 1u)) >> 16;   // RNE, finite inputs
  return (unsigned short)r;
}

// ---------------- kernel 1: convert q,k,v -> bf16 (+ V^T, + W^T) ----------------
// blocks 0..511: 64x64 tile (j0 x d-col-range) of head h; block 512: Wt
__global__ __launch_bounds__(256) void convert_kernel(
    const float* __restrict__ q, const float* __restrict__ k, const float* __restrict__ v,
    const float* __restrict__ Wi, const float* __restrict__ Wf,
    unsigned short* __restrict__ qb, unsigned short* __restrict__ kb,
    unsigned short* __restrict__ vb, unsigned short* __restrict__ vt,
    unsigned short* __restrict__ wt)
{
  const int b = blockIdx.x;
  if (b == 512) {
    for (int idx = threadIdx.x; idx < 16*3*E; idx += 256) {
      int n = idx / (3*E), e = idx - n*(3*E);
      float val = (n < 8) ? Wi[e*NH + n] : Wf[e*NH + (n-8)];
      wt[idx] = f2bf(val);
    }
    return;
  }
  __shared__ float Ts[64][65];
  const int j0 = (b & 31) * 64;
  const int d0 = ((b >> 5) & 1) * 64;
  const int h  = b >> 6;
  const int c = threadIdx.x & 63, r4 = threadIdx.x >> 6;
  #pragma unroll
  for (int rr = 0; rr < 16; ++rr) {
    int r = r4*16 + rr;
    size_t off = (size_t)(j0 + r)*E + h*DH + d0 + c;
    float qv = q[off], kv = k[off], vv = v[off];
    qb[off] = f2bf(qv); kb[off] = f2bf(kv); vb[off] = f2bf(vv);
    Ts[r][c] = vv;
  }
  __syncthreads();
  #pragma unroll
  for (int rr = 0; rr < 16; ++rr) {
    int r = r4*16 + rr;
    vt[(size_t)(h*DH + d0 + r)*S + j0 + c] = f2bf(Ts[c][r]);
  }
}

// ---------------- kernel 2: gate GEMM via MFMA ----------------
// [2048 x 3072] @ [3072 x 16] -> i_pre (n<8), log_sigmoid(f_pre) (n>=8)
__global__ __launch_bounds__(256) void gates_kernel(
    const unsigned short* __restrict__ qb, const unsigned short* __restrict__ kb,
    const unsigned short* __restrict__ vb, const unsigned short* __restrict__ wt,
    const float* __restrict__ bi, const float* __restrict__ bfg,
    float* __restrict__ ipre, float* __restrict__ lsf)
{
  const int wv = threadIdx.x >> 6, lane = threadIdx.x & 63;
  const int m0 = (blockIdx.x * 4 + wv) * 16;            // 32 blocks x 4 waves = 128 tiles
  const int tr = lane & 15;                             // A row / B col
  const int ks = (lane >> 4) * 8;                       // k offset within K=32
  f32x4 acc = {0.f, 0.f, 0.f, 0.f};
  const unsigned short* srcs[3] = {qb, kb, vb};
  #pragma unroll
  for (int p = 0; p < 3; ++p) {
    const unsigned short* X = srcs[p];
    for (int e0 = 0; e0 < E; e0 += 32) {
      short8 af = *reinterpret_cast<const short8*>(X  + (size_t)(m0 + tr)*E + e0 + ks);
      short8 bf8 = *reinterpret_cast<const short8*>(wt + (size_t)tr*(3*E) + p*E + e0 + ks);
      acc = __builtin_amdgcn_mfma_f32_16x16x32_bf16(af, bf8, acc, 0, 0, 0);
    }
  }
  const int n = lane & 15, rbase = (lane >> 4) * 4;
  #pragma unroll
  for (int r = 0; r < 4; ++r) {
    int t = m0 + rbase + r;
    float val = acc[r];
    if (n < 8) {
      ipre[n*S + t] = val + bi[n];
    } else {
      float fp = val + bfg[n-8];
      lsf[(n-8)*S + t] = fminf(fp, 0.f) - log1pf(__expf(-fabsf(fp)));
    }
  }
}

// ---------------- kernel 3: per-head scans -> a2 = a/ln2, m2 = m/ln2 ----------------
__global__ __launch_bounds__(256) void scan_kernel(
    const float* __restrict__ ipre, const float* __restrict__ lsf,
    float* __restrict__ a2_out, float* __restrict__ m2_out)
{
  const int h = blockIdx.x, tid = threadIdx.x;
  const int lane = tid & 63, wv = tid >> 6;
  constexpr int PER = S / 256;  // 8
  const int base = h*S + tid*PER;
  __shared__ float wred[4], wmax[4];

  float c[PER];
  float run = 0.f;
  #pragma unroll
  for (int u = 0; u < PER; u++) { run += lsf[base+u]; c[u] = run; }
  // wave inclusive scan (sum)
  float s = run;
  #pragma unroll
  for (int off = 1; off < 64; off <<= 1) {
    float t = __shfl_up(s, off);
    if (lane >= off) s += t;
  }
  if (lane == 63) wred[wv] = s;
  __syncthreads();
  float wpre = 0.f;
  for (int i = 0; i < wv; i++) wpre += wred[i];
  const float excl = wpre + (s - run);

  float av[PER], mloc[PER];
  float lm = -INFINITY;
  #pragma unroll
  for (int u = 0; u < PER; u++) {
    c[u] += excl;
    av[u] = ipre[base+u] - c[u];
    lm = fmaxf(lm, av[u]);
    mloc[u] = lm;
  }
  // wave inclusive scan (max)
  float sm_ = lm;
  #pragma unroll
  for (int off = 1; off < 64; off <<= 1) {
    float t = __shfl_up(sm_, off);
    if (lane >= off) sm_ = fmaxf(sm_, t);
  }
  if (lane == 63) wmax[wv] = sm_;
  __syncthreads();
  float wpm = -INFINITY;
  for (int i = 0; i < wv; i++) wpm = fmaxf(wpm, wmax[i]);
  float prev = __shfl_up(sm_, 1);
  if (lane == 0) prev = -INFINITY;
  const float exclm = fmaxf(wpm, prev);
  #pragma unroll
  for (int u = 0; u < PER; u++) {
    float m = fmaxf(exclm, mloc[u]);
    a2_out[base+u] = av[u] * INV_LN2;
    m2_out[base+u] = m * INV_LN2;
  }
}

// ---------------- kernel 4: MFMA causal decay-attention + LN ----------------
// 512 blocks: head = b&7 (XCD-affine), qt = 63 - (b>>3) (longest first)
__global__ __launch_bounds__(256, 2) void attn_kernel(
    const unsigned short* __restrict__ qb, const unsigned short* __restrict__ kb,
    const unsigned short* __restrict__ vt,
    const float* __restrict__ a2g, const float* __restrict__ m2g,
    const float* __restrict__ ln, float* __restrict__ out)
{
  const int qt = 63 - (int)(blockIdx.x >> 3);
  const int h  = blockIdx.x & 7;
  const int tid = threadIdx.x;
  const int w = tid >> 6, lane = tid & 63, l31 = lane & 31, half = lane >> 5;
  const int qi0 = qt * 32;
  const int niter = (qt + 4) >> 2;
  const int jcol_off = 32*w + l31;

  __shared__ short Ps[2][32][132];
  __shared__ float Hs[32][132];
  __shared__ float mrow[32];

  if (tid < 32) mrow[tid] = m2g[h*S + qi0 + tid];

  short8 qf[8];
  #pragma unroll
  for (int s = 0; s < 8; ++s)
    qf[s] = *reinterpret_cast<const short8*>(
        qb + (size_t)(qi0 + l31)*E + h*DH + 16*s + 8*half);

  __syncthreads();
  float mreg[16];
  #pragma unroll
  for (int r = 0; r < 16; ++r) mreg[r] = mrow[(r&3) + 8*(r>>2) + 4*half];

  f32x16 acc = {0,0,0,0,0,0,0,0,0,0,0,0,0,0,0,0};

  short8 kA[8], vA[8], kB[8], vB[8];
  float aA, aB;
  #pragma unroll
  for (int s = 0; s < 8; ++s) {
    kA[s] = *reinterpret_cast<const short8*>(
        kb + (size_t)(0 + jcol_off)*E + h*DH + 16*s + 8*half);
    vA[s] = *reinterpret_cast<const short8*>(
        vt + (size_t)(h*DH + jcol_off)*S + 0 + 16*s + 8*half);
  }
  aA = a2g[h*S + jcol_off];

  auto body = [&](int jt, short8 (&kfu)[8], short8 (&vfu)[8], float aju,
                  short8 (&kfn)[8], short8 (&vfn)[8], float& ajn) {
    const int j0 = jt * 128;
    int jn = j0 + 128;
    if (jn > S - 128) jn = j0;           // clamp: harmless reload, no OOB
    #pragma unroll
    for (int s = 0; s < 8; ++s) {
      kfn[s] = *reinterpret_cast<const short8*>(
          kb + (size_t)(jn + jcol_off)*E + h*DH + 16*s + 8*half);
      vfn[s] = *reinterpret_cast<const short8*>(
          vt + (size_t)(h*DH + jcol_off)*S + jn + 16*s + 8*half);
    }
    ajn = a2g[h*S + jn + jcol_off];

    f32x16 qk = {0,0,0,0,0,0,0,0,0,0,0,0,0,0,0,0};
    #pragma unroll
    for (int s = 0; s < 8; ++s)
      qk = __builtin_amdgcn_mfma_f32_32x32x16_bf16(qf[s], kfu[s], qk, 0, 0, 0);

    const int jcol = j0 + jcol_off;
    const int buf = jt & 1;
    #pragma unroll
    for (int r = 0; r < 16; ++r) {
      const int iloc = (r&3) + 8*(r>>2) + 4*half;
      float d = fminf(aju - mreg[r], 0.f);
      float pv = (jcol <= qi0 + iloc) ? qk[r] * exp2f(d) : 0.f;
      Ps[buf][iloc][jcol_off] = (short)f2bf(pv);
    }
    __syncthreads();
    #pragma unroll
    for (int s = 0; s < 8; ++s) {
      short8 pf = *reinterpret_cast<const short8*>(&Ps[buf][l31][16*s + 8*half]);
      acc = __builtin_amdgcn_mfma_f32_32x32x16_bf16(pf, vfu[s], acc, 0, 0, 0);
    }
  };

  int jt = 0;
  for (; jt + 1 < niter; jt += 2) {
    body(jt,     kA, vA, aA, kB, vB, aB);
    body(jt + 1, kB, vB, aB, kA, vA, aA);
  }
  if (jt < niter) body(jt, kA, vA, aA, kB, vB, aB);

  // epilogue: LN over DH (normalizer is a per-row positive scale -> cancels)
  __syncthreads();
  #pragma unroll
  for (int r = 0; r < 16; ++r)
    Hs[(r&3) + 8*(r>>2) + 4*half][32*w + l31] = acc[r];
  __syncthreads();
  {
    const int row = tid >> 3, seg = tid & 7;
    float vals[16];
    #pragma unroll
    for (int c4 = 0; c4 < 4; ++c4) {
      float4 v4 = *reinterpret_cast<const float4*>(&Hs[row][seg*16 + c4*4]);
      vals[c4*4+0]=v4.x; vals[c4*4+1]=v4.y; vals[c4*4+2]=v4.z; vals[c4*4+3]=v4.w;
    }
    float s1 = 0.f, s2 = 0.f;
    #pragma unroll
    for (int c = 0; c < 16; ++c) { s1 += vals[c]; s2 = fmaf(vals[c], vals[c], s2); }
    #pragma unroll
    for (int off = 1; off < 8; off <<= 1) {
      s1 += __shfl_xor(s1, off);
      s2 += __shfl_xor(s2, off);
    }
    const float mu = s1 * (1.f/128.f);
    float var = fmaxf(s2 * (1.f/128.f) - mu*mu, 0.f);
    const float rs = rsqrtf(var + EPSF);
    const size_t ob = (size_t)(qi0 + row)*E + h*DH + seg*16;
    #pragma unroll
    for (int c = 0; c < 16; ++c)
      out[ob + c] = (vals[c] - mu) * rs * ln[h*DH + seg*16 + c];
  }
}

extern "C" void kernel_launch(void* const* d_in, const int* in_sizes, int n_in,
                              void* d_out, int out_size, void* d_ws, size_t ws_size,
                              hipStream_t stream) {
  const float* q  = (const float*)d_in[0];
  const float* k  = (const float*)d_in[1];
  const float* v  = (const float*)d_in[2];
  const float* Wi = (const float*)d_in[3];
  const float* bi = (const float*)d_in[4];
  const float* Wf = (const float*)d_in[5];
  const float* bf = (const float*)d_in[6];
  const float* ln = (const float*)d_in[7];
  float* out = (float*)d_out;

  // ws: qb 4MB | kb 4MB | vb 4MB | vt 4MB | wt 96KB | 4 x 64KB f32  (~16.4 MB)
  char* base = (char*)d_ws;
  unsigned short* qb = (unsigned short*)(base);
  unsigned short* kb = (unsigned short*)(base + (size_t)S*E*2);
  unsigned short* vb = (unsigned short*)(base + (size_t)S*E*4);
  unsigned short* vt = (unsigned short*)(base + (size_t)S*E*6);
  unsigned short* wt = (unsigned short*)(base + (size_t)S*E*8);
  float* fbase = (float*)(base + (size_t)S*E*8 + 16*3*E*2);
  float* ipre = fbase;
  float* lsf  = fbase + 1*NH*S;
  float* a2   = fbase + 2*NH*S;
  float* m2   = fbase + 3*NH*S;

  convert_kernel<<<dim3(513), dim3(256), 0, stream>>>(q, k, v, Wi, Wf, qb, kb, vb, vt, wt);
  gates_kernel<<<dim3(32), dim3(256), 0, stream>>>(qb, kb, vb, wt, bi, bf, ipre, lsf);
  scan_kernel<<<dim3(NH), dim3(256), 0, stream>>>(ipre, lsf, a2, m2);
  attn_kernel<<<dim3(512), dim3(256), 0, stream>>>(qb, kb, vt, a2, m2, ln, out);
}